// Round 6
// baseline (982.500 us; speedup 1.0000x reference)
//
#include <hip/hip_runtime.h>
#include <hip/hip_bf16.h>

typedef unsigned short u16;
typedef unsigned int   u32;
typedef _Float16 h2 __attribute__((ext_vector_type(2)));
typedef short s8v __attribute__((ext_vector_type(8)));
typedef float f4v __attribute__((ext_vector_type(4)));
typedef u16 u16x4 __attribute__((ext_vector_type(4)));

#define N_NODES 50000
#define N_EDGES 800000

// binned bucket construction
#define RPB   250        // receivers per bin
#define NBINS 200
#define EPB   4096       // edges per block in binning kernels
#define NBB   ((N_EDGES+EPB-1)/EPB)   // 196

// ---- ws layout (u32 units) ----
#define WB_W1H  0        // [64][4] u32 half2 (fp16 pairs of W1 columns)
#define WB_B1   256      // [64] f32
#define WB_W2F  320      // 5120 bf16 = 2560 u32, MFMA B-frag layout
#define WB_WINS 2880
#define WB_WINV 3136
#define WB_WOS  3392
#define WB_WOV  4416
#define WB_SCS  5184
#define WB_SCV  7232
#define WB_FLAG 8256
#define OFF_SV16 8260    // [50000][16][4] u16 (xs,x0,x1,x2)
#define IDX_BCNT 1608260 // 200 ints
#define IDX_BOF2 1608516 // 200 ints
#define IDX_BCUR 1608772 // 200 ints
#define IDX_OFFS 1658260 // 50001 ints
#define IDX_BUCK 1758262 // 800,000 int
#define IDX_EEID 2558264 // 800,000 u32 (bin-grouped edge ids)
#define OFF_ER16 3358264 // 800,000 u16 (bin-grouped receivers)

__device__ __forceinline__ float bf2f(u16 v){
  union { u32 u; float f; } x; x.u = ((u32)v) << 16; return x.f;
}
__device__ __forceinline__ u16 f2bf(float f){
  u32 u = __float_as_uint(f);
  u32 lsb = (u >> 16) & 1u;
  u32 r = u + 0x7fffu + lsb;
  return (u16)(r >> 16);
}
__device__ __forceinline__ float ldx(const void* p, long long i, int isf){
  return isf ? ((const float*)p)[i] : bf2f(((const u16*)p)[i]);
}
__device__ __forceinline__ u32 pkh2(float a, float b){
  union { u32 u; h2 v; } x; x.v.x = (_Float16)a; x.v.y = (_Float16)b; return x.u;
}
__device__ __forceinline__ float dot2(h2 a, u32 w, float c){
  union { u32 u; h2 v; } x; x.u = w;
#if __has_builtin(__builtin_amdgcn_fdot2)
  return __builtin_amdgcn_fdot2(a, x.v, c, false);
#else
  return c + (float)a.x*(float)x.v.x + (float)a.y*(float)x.v.y;
#endif
}
__device__ __forceinline__ float sigmoidf_(float x){ return 1.f/(1.f + __expf(-x)); }

__global__ void detect_dtype(const u32* __restrict__ remb_raw, int* __restrict__ flag){
  int t = threadIdx.x;           // 64 lanes, one word each
  u32 w = remb_raw[t];
  u32 lo = w & 0xffffu, hi = w >> 16;
  int okl = ((lo & 0x8000u) == 0) && (((lo >> 7) & 0xffu) <= 126u);
  int okh = ((hi & 0x8000u) == 0) && (((hi >> 7) & 0xffu) <= 126u);
  unsigned long long bad = __ballot(!(okl && okh));
  if (t == 0) *flag = (bad != 0ull) ? 1 : 0;
}

__global__ void prep_weights(const void* __restrict__ w1, const void* __restrict__ b1g,
                             const void* __restrict__ w2, const void* __restrict__ wins,
                             const void* __restrict__ winv, const void* __restrict__ wos,
                             const void* __restrict__ wov, const void* __restrict__ scs,
                             const void* __restrict__ scv, float* __restrict__ wbuf,
                             const int* __restrict__ flag){
  int t = threadIdx.x;
  int isf = *flag;
  u32* w1h  = (u32*)(wbuf + WB_W1H);
  u16* w2f  = (u16*)(wbuf + WB_W2F);
  for (int idx=t; idx<256;  idx+=256){
    int j = idx>>2, ip = idx&3;
    w1h[idx] = pkh2(ldx(w1, (2*ip)*64+j, isf), ldx(w1, (2*ip+1)*64+j, isf));
  }
  for (int idx=t; idx<64;   idx+=256){ wbuf[WB_B1+idx]  = ldx(b1g, idx, isf); }
  // MFMA B-frag layout for 16x16x32 bf16: lane holds B[k=(lane>>4)*8+j][n=lane&15]
  for (int idx=t; idx<5120; idx+=256){
    int tt = idx >> 10;           // N-tile 0..4
    int rem = idx & 1023;
    int kh = rem >> 9;            // K-half 0..1
    int rem2 = rem & 511;
    int ln = rem2 >> 3, j = rem2 & 7;
    int k = kh*32 + (ln>>4)*8 + j;
    int o = tt*16 + (ln&15);
    w2f[idx] = f2bf(ldx(w2, (long long)k*80 + o, isf));
  }
  for (int idx=t; idx<256;  idx+=256){ wbuf[WB_WINS+idx] = ldx(wins, idx, isf); }
  for (int idx=t; idx<256;  idx+=256){ wbuf[WB_WINV+idx] = ldx(winv, idx, isf); }
  for (int idx=t; idx<1024; idx+=256){ wbuf[WB_WOS+idx]  = ldx(wos, idx, isf); }
  for (int idx=t; idx<768;  idx+=256){ wbuf[WB_WOV+idx]  = ldx(wov, idx, isf); }
  for (int idx=t; idx<2048; idx+=256){ wbuf[WB_SCS+idx]  = ldx(scs, idx, isf); }
  for (int idx=t; idx<1024; idx+=256){ wbuf[WB_SCV+idx]  = ldx(scv, idx, isf); }
}

// one node per thread; fully vectorized 16B loads/stores; 64-thread blocks for CU spread
__global__ void __launch_bounds__(64) node_pre(
    const void* __restrict__ ns_g, const void* __restrict__ nv_g,
    const float* __restrict__ wbuf, u16* __restrict__ sv16,
    const int* __restrict__ flag){
  int n = blockIdx.x*64 + threadIdx.x;
  if (n >= N_NODES) return;
  int isf = *flag;
  float a[16], b[48];
  if (isf){
    const f4v* pa = (const f4v*)ns_g + (size_t)n*4;
    #pragma unroll
    for (int k=0;k<4;k++){
      f4v v = pa[k];
      a[k*4]=v[0]; a[k*4+1]=v[1]; a[k*4+2]=v[2]; a[k*4+3]=v[3];
    }
    const f4v* pb = (const f4v*)nv_g + (size_t)n*12;
    #pragma unroll
    for (int k=0;k<12;k++){
      f4v v = pb[k];
      b[k*4]=v[0]; b[k*4+1]=v[1]; b[k*4+2]=v[2]; b[k*4+3]=v[3];
    }
  } else {
    const s8v* pa = (const s8v*)ns_g + (size_t)n*2;
    #pragma unroll
    for (int k=0;k<2;k++){
      s8v v = pa[k];
      #pragma unroll
      for (int j=0;j<8;j++) a[k*8+j] = bf2f((u16)v[j]);
    }
    const s8v* pb = (const s8v*)nv_g + (size_t)n*6;
    #pragma unroll
    for (int k=0;k<6;k++){
      s8v v = pb[k];
      #pragma unroll
      for (int j=0;j<8;j++) b[k*8+j] = bf2f((u16)v[j]);
    }
  }
  const float* wins = wbuf + WB_WINS;
  const float* winv = wbuf + WB_WINV;
  float s[16];
  #pragma unroll
  for (int w=0;w<16;w++) s[w]=0.f;
  #pragma unroll
  for (int u=0;u<16;u++){
    float au = a[u];
    #pragma unroll
    for (int w=0;w<16;w++) s[w] += au * wins[u*16+w];
  }
  float v0[16], v1[16], v2[16];
  #pragma unroll
  for (int w=0;w<16;w++){ v0[w]=0.f; v1[w]=0.f; v2[w]=0.f; }
  #pragma unroll
  for (int u=0;u<16;u++){
    float bu0=b[u*3], bu1=b[u*3+1], bu2=b[u*3+2];
    #pragma unroll
    for (int w=0;w<16;w++){
      float wv = winv[u*16+w];
      v0[w] += bu0*wv; v1[w] += bu1*wv; v2[w] += bu2*wv;
    }
  }
  s8v* svp = (s8v*)(sv16 + (size_t)n*64);
  #pragma unroll
  for (int w=0;w<16;w+=2){
    s8v pk;
    pk[0]=(short)f2bf(s[w]);   pk[1]=(short)f2bf(v0[w]);
    pk[2]=(short)f2bf(v1[w]);  pk[3]=(short)f2bf(v2[w]);
    pk[4]=(short)f2bf(s[w+1]); pk[5]=(short)f2bf(v0[w+1]);
    pk[6]=(short)f2bf(v1[w+1]);pk[7]=(short)f2bf(v2[w+1]);
    svp[w>>1] = pk;
  }
}

// ---- binned bucket construction ----
__global__ void __launch_bounds__(256) bin_count(const int* __restrict__ receivers,
                                                 int* __restrict__ bcnt){
  __shared__ int lcnt[NBINS];
  int t = threadIdx.x;
  for (int i=t;i<NBINS;i+=256) lcnt[i]=0;
  __syncthreads();
  int base = blockIdx.x*EPB;
  for (int i=t;i<EPB;i+=256){
    int e = base+i;
    if (e<N_EDGES) atomicAdd(&lcnt[receivers[e]/RPB],1);
  }
  __syncthreads();
  for (int i=t;i<NBINS;i+=256) if (lcnt[i]) atomicAdd(&bcnt[i], lcnt[i]);
}

__global__ void bin_scan(const int* __restrict__ bcnt, int* __restrict__ binoff,
                         int* __restrict__ bincur, int* __restrict__ offs){
  __shared__ int lds[NBINS];
  int t=threadIdx.x;
  if (t<NBINS) lds[t]=bcnt[t];
  __syncthreads();
  for (int off=1; off<NBINS; off<<=1){
    int v = (t<NBINS && t>=off)? lds[t-off] : 0;
    __syncthreads();
    if (t<NBINS) lds[t]+=v;
    __syncthreads();
  }
  if (t<NBINS){ int ex = lds[t]-bcnt[t]; binoff[t]=ex; bincur[t]=ex; }
  if (t==0) offs[N_NODES] = N_EDGES;
}

__global__ void __launch_bounds__(256) bin_scatter(const int* __restrict__ receivers,
                 int* __restrict__ bincur, u32* __restrict__ eeid, u16* __restrict__ er){
  __shared__ int lcnt[NBINS], loff[NBINS], lcur[NBINS], gbase[NBINS];
  __shared__ u32 seid[EPB];
  __shared__ u16 sr[EPB];
  int t = threadIdx.x;
  for (int i=t;i<NBINS;i+=256) lcnt[i]=0;
  __syncthreads();
  int base = blockIdx.x*EPB;
  int r_[16];
  #pragma unroll
  for (int k=0;k<16;k++){
    int e = base + t + k*256;
    r_[k] = (e<N_EDGES)? receivers[e] : -1;
    if (r_[k]>=0) atomicAdd(&lcnt[r_[k]/RPB],1);
  }
  __syncthreads();
  if (t<NBINS) loff[t]=lcnt[t];
  __syncthreads();
  for (int off=1; off<NBINS; off<<=1){
    int v=(t<NBINS&&t>=off)?loff[t-off]:0;
    __syncthreads();
    if (t<NBINS) loff[t]+=v;
    __syncthreads();
  }
  if (t<NBINS){
    int ex=loff[t]-lcnt[t]; loff[t]=ex; lcur[t]=ex;
    gbase[t] = lcnt[t] ? atomicAdd(&bincur[t], lcnt[t]) : 0;
  }
  __syncthreads();
  #pragma unroll
  for (int k=0;k<16;k++){
    if (r_[k]>=0){
      int b=r_[k]/RPB;
      int p=atomicAdd(&lcur[b],1);
      seid[p]=(u32)(base + t + k*256);
      sr[p]=(u16)r_[k];
    }
  }
  __syncthreads();
  int rem = N_EDGES - base;
  int tot = rem < EPB ? rem : EPB;
  for (int i=t;i<tot;i+=256){
    int b = sr[i]/RPB;
    int dst = gbase[b] + (i - loff[b]);
    eeid[dst]=seid[i]; er[dst]=sr[i];
  }
}

__global__ void __launch_bounds__(256) bin_finalize(const u32* __restrict__ eeid,
        const u16* __restrict__ er, const int* __restrict__ binoff,
        const int* __restrict__ bcnt, int* __restrict__ offs, int* __restrict__ bucket){
  __shared__ int deg[RPB], pfx[RPB], lcur[RPB];
  int b=blockIdx.x, t=threadIdx.x;
  int beg=binoff[b], cnt=bcnt[b];
  for (int i=t;i<RPB;i+=256) deg[i]=0;
  __syncthreads();
  int r0=b*RPB;
  for (int i=t;i<cnt;i+=256) atomicAdd(&deg[er[beg+i]-r0],1);
  __syncthreads();
  if (t<RPB) pfx[t]=deg[t];
  __syncthreads();
  for (int off=1; off<RPB; off<<=1){
    int v=(t<RPB&&t>=off)?pfx[t-off]:0;
    __syncthreads();
    if (t<RPB) pfx[t]+=v;
    __syncthreads();
  }
  if (t<RPB){
    int ex=pfx[t]-deg[t]; pfx[t]=ex; lcur[t]=ex;
    offs[r0+t]=beg+ex;
  }
  __syncthreads();
  for (int i=t;i<cnt;i+=256){
    int rr = er[beg+i]-r0;
    int k = atomicAdd(&lcur[rr],1);
    bucket[beg+k] = (int)eeid[beg+i];
  }
}

// fused middle: per block = 16 receivers (contiguous rank range).
// Phase A: MFMA w per 16-edge tile (w stays in regs, full f32).
// Phase B: gather Y/sender/sv, accumulate 11 values into per-receiver LDS bins.
// Epilogue: dense per-node output (former pass2_epilogue).
__global__ void __launch_bounds__(256) fused_edge(
    const int* __restrict__ bucket, const int* __restrict__ offs,
    const void* __restrict__ remb, const void* __restrict__ edge_sh,
    const int* __restrict__ senders, const u16* __restrict__ sv16,
    const float* __restrict__ wbuf, const void* __restrict__ ns_g,
    const void* __restrict__ nv_g, const int* __restrict__ species,
    void* __restrict__ out, const int* __restrict__ flag){
  __shared__ u16 hlds[4*16*72];          // 4 waves x 16 edges x 64 h (+8 pad)
  __shared__ float bins[16*176];
  __shared__ int offs_l[17];
  __shared__ float sb2[16*16 + 16*48];   // ns | vin staging
  int tid = threadIdx.x;
  int lane = tid & 63, wid = tid >> 6;
  int isf = *flag;
  int n0 = blockIdx.x * 16;              // 3125*16 = 50000 exact
  if (tid < 17) offs_l[tid] = offs[n0 + tid];
  for (int i=tid; i<16*176; i+=256) bins[i] = 0.f;
  __syncthreads();
  // epilogue staging (independent of main loop)
  {
    float* nsb = sb2;
    for (int i=tid; i<256; i+=256)
      nsb[i] = ldx(ns_g, (long long)n0*16 + i, isf);
    float* vinb = sb2 + 256;
    for (int i=tid; i<768; i+=256)
      vinb[i] = ldx(nv_g, (long long)n0*48 + i, isf);
  }
  int beg = offs_l[0], end = offs_l[16];
  int cnt = end - beg;
  u16* hw = hlds + wid*(16*72);
  int e = lane & 15, q = lane >> 4;
  const u32* w1h = (const u32*)(wbuf + WB_W1H);
  const float* b1 = wbuf + WB_B1;
  const u16* w2f = (const u16*)(wbuf + WB_W2F);
  s8v bfr[5][2];
  #pragma unroll
  for (int t=0;t<5;t++)
    #pragma unroll
    for (int kh=0;kh<2;kh++)
      bfr[t][kh] = *(const s8v*)(w2f + ((t*2+kh)*64 + lane)*8);

  for (int tb = wid*16; tb < cnt; tb += 64){
    int er = beg + tb + e;
    int eid = (er < end) ? bucket[er] : 0;
    float re[8];
    if (isf){
      f4v ra = ((const f4v*)remb)[(size_t)eid*2];
      f4v rb = ((const f4v*)remb)[(size_t)eid*2+1];
      re[0]=ra[0]; re[1]=ra[1]; re[2]=ra[2]; re[3]=ra[3];
      re[4]=rb[0]; re[5]=rb[1]; re[6]=rb[2]; re[7]=rb[3];
    } else {
      s8v r8 = ((const s8v*)remb)[eid];
      #pragma unroll
      for (int i=0;i<8;i++) re[i] = bf2f((u16)r8[i]);
    }
    h2 reh[4];
    #pragma unroll
    for (int ip=0;ip<4;ip++){ reh[ip].x=(_Float16)re[2*ip]; reh[ip].y=(_Float16)re[2*ip+1]; }
    // ensure previous iteration's LDS reads retired before overwriting hw
    asm volatile("s_waitcnt lgkmcnt(0)" ::: "memory");
    #pragma unroll
    for (int jj=0;jj<16;jj++){
      int j = q*16 + jj;
      float a = b1[j];
      #pragma unroll
      for (int ip=0;ip<4;ip++) a = dot2(reh[ip], w1h[j*4+ip], a);
      a = a * sigmoidf_(a);
      hw[e*72 + j] = f2bf(a);
    }
    asm volatile("s_waitcnt lgkmcnt(0)" ::: "memory");  // wave-local LDS exchange
    f4v acc[5];
    #pragma unroll
    for (int t=0;t<5;t++) acc[t] = (f4v){0.f,0.f,0.f,0.f};
    #pragma unroll
    for (int kh=0;kh<2;kh++){
      s8v af = *(const s8v*)(hw + e*72 + kh*32 + q*8);
      #pragma unroll
      for (int t=0;t<5;t++)
        acc[t] = __builtin_amdgcn_mfma_f32_16x16x32_bf16(af, bfr[t][kh], acc[t], 0,0,0);
    }
    // phase B: C layout col=lane&15 (=u), row=q*4+r (=edge in tile)
    int u = e;
    #pragma unroll
    for (int r=0;r<4;r++){
      int rank2 = beg + tb + q*4 + r;
      if (rank2 < end){
        int eidr = __shfl(eid, q*4 + r);
        float Y0,Yv0,Yv1,Yv2;
        if (isf){
          f4v y = ((const f4v*)edge_sh)[eidr];
          Y0=y[0]; Yv0=y[1]; Yv1=y[2]; Yv2=y[3];
        } else {
          u16x4 y = ((const u16x4*)edge_sh)[eidr];
          Y0=bf2f(y[0]); Yv0=bf2f(y[1]); Yv1=bf2f(y[2]); Yv2=bf2f(y[3]);
        }
        int snd = senders[eidr];
        u16x4 sv = *(const u16x4*)(sv16 + ((size_t)snd*16 + u)*4);
        float xs=bf2f(sv[0]), x0=bf2f(sv[1]), x1=bf2f(sv[2]), x2=bf2f(sv[3]);
        float w0=acc[0][r], w1=acc[1][r], w2=acc[2][r], w3=acc[3][r], w4=acc[4][r];
        // receiver index within block: upper-bound search over cached offsets
        int g = 0;
        if (rank2 >= offs_l[g+8]) g += 8;
        if (rank2 >= offs_l[g+4]) g += 4;
        if (rank2 >= offs_l[g+2]) g += 2;
        if (rank2 >= offs_l[g+1]) g += 1;
        float* bp = bins + g*176;
        float t1 = w2*xs, t2 = w3*Y0;
        atomicAdd(&bp[u],      w0*xs*Y0);
        atomicAdd(&bp[16+u],   w1*(x0*Yv0 + x1*Yv1 + x2*Yv2));
        atomicAdd(&bp[32+u],   t1*Yv0);
        atomicAdd(&bp[80+u],   t1*Yv1);
        atomicAdd(&bp[128+u],  t1*Yv2);
        atomicAdd(&bp[48+u],   t2*x0);
        atomicAdd(&bp[96+u],   t2*x1);
        atomicAdd(&bp[144+u],  t2*x2);
        atomicAdd(&bp[64+u],   w4*(x1*Yv2 - x2*Yv1));
        atomicAdd(&bp[112+u],  w4*(x2*Yv0 - x0*Yv2));
        atomicAdd(&bp[160+u],  w4*(x0*Yv1 - x1*Yv0));
      }
    }
  }
  __syncthreads();

  // ---- epilogue: 16 threads per node ----
  int g2 = tid >> 4, u2 = tid & 15;
  int nn = n0 + g2;
  const float* bin  = bins + g2*176;
  const float* nsb  = sb2 + g2*16;
  const float* vinb = sb2 + 256 + g2*48;
  int sp = species[nn];
  const float* wos = wbuf + WB_WOS;
  const float* scs = wbuf + WB_SCS + sp*512;
  const float* wov = wbuf + WB_WOV;
  const float* scv = wbuf + WB_SCV + sp*256;
  float p0 = 0.f, p1 = 0.f;
  #pragma unroll
  for (int j=0;j<32;j++){
    float a = bin[j]*0.25f;
    p0 += a*wos[j*32+u2];
    p1 += a*wos[j*32+16+u2];
  }
  #pragma unroll
  for (int j=0;j<16;j++){
    float nu = nsb[j];
    p0 += nu*scs[j*32+u2];
    p1 += nu*scs[j*32+16+u2];
  }
  float gate = sigmoidf_(p1);
  float os = p0*sigmoidf_(p0) + nsb[u2];
  float pv0, pv1, pv2;
  {
    float a0=0.f, a1=0.f, a2=0.f;
    #pragma unroll
    for (int j=0;j<48;j++){
      float wv = wov[j*16+u2];
      a0 += bin[32 + 0*48 + j]*0.25f*wv;
      a1 += bin[32 + 1*48 + j]*0.25f*wv;
      a2 += bin[32 + 2*48 + j]*0.25f*wv;
    }
    #pragma unroll
    for (int j=0;j<16;j++){
      float sv = scv[j*16+u2];
      a0 += vinb[j*3+0]*sv;
      a1 += vinb[j*3+1]*sv;
      a2 += vinb[j*3+2]*sv;
    }
    pv0 = a0*gate + vinb[u2*3+0];
    pv1 = a1*gate + vinb[u2*3+1];
    pv2 = a2*gate + vinb[u2*3+2];
  }
  if (isf){
    float* orow = (float*)out + (size_t)nn*64;
    orow[u2] = os;
    orow[16 + u2*3 + 0] = pv0;
    orow[16 + u2*3 + 1] = pv1;
    orow[16 + u2*3 + 2] = pv2;
  } else {
    u16* orow = (u16*)out + (size_t)nn*64;
    orow[u2] = f2bf(os);
    orow[16 + u2*3 + 0] = f2bf(pv0);
    orow[16 + u2*3 + 1] = f2bf(pv1);
    orow[16 + u2*3 + 2] = f2bf(pv2);
  }
}

extern "C" void kernel_launch(void* const* d_in, const int* in_sizes, int n_in,
                              void* d_out, int out_size, void* d_ws, size_t ws_size,
                              hipStream_t stream){
  const void* node_scalars = d_in[0];
  const void* node_vectors = d_in[1];
  const void* edge_sh      = d_in[2];
  const void* radial_emb   = d_in[3];
  const int* senders      = (const int*)d_in[4];
  const int* receivers    = (const int*)d_in[5];
  const int* species      = (const int*)d_in[6];
  const void* W_in_s  = d_in[7];
  const void* W_in_v  = d_in[8];
  const void* mlp_w1  = d_in[9];
  const void* mlp_b1  = d_in[10];
  const void* mlp_w2  = d_in[11];
  const void* W_out_s = d_in[12];
  const void* W_out_v = d_in[13];
  const void* sc_s    = d_in[14];
  const void* sc_v    = d_in[15];

  float* wsf  = (float*)d_ws;
  int*   wsi  = (int*)d_ws;
  u32*   wsu  = (u32*)d_ws;
  float* wbuf = wsf;
  u16*   sv16 = (u16*)(wsu + OFF_SV16);
  int*   bcnt = wsi + IDX_BCNT;
  int*   bof2 = wsi + IDX_BOF2;
  int*   bcur = wsi + IDX_BCUR;
  int*   offs = wsi + IDX_OFFS;
  int*   buck = wsi + IDX_BUCK;
  u32*   eeid = wsu + IDX_EEID;
  u16*   er16 = (u16*)(wsu + OFF_ER16);
  int*   flag = (int*)(wbuf + WB_FLAG);

  detect_dtype<<<1,64,0,stream>>>((const u32*)radial_emb, flag);
  hipMemsetAsync(bcnt, 0, NBINS*sizeof(int), stream);
  prep_weights<<<1,256,0,stream>>>(mlp_w1, mlp_b1, mlp_w2, W_in_s, W_in_v,
                                   W_out_s, W_out_v, sc_s, sc_v, wbuf, flag);
  node_pre<<<(N_NODES+63)/64,64,0,stream>>>(node_scalars, node_vectors, wbuf,
                                            sv16, flag);
  bin_count<<<NBB,256,0,stream>>>(receivers, bcnt);
  bin_scan<<<1,256,0,stream>>>(bcnt, bof2, bcur, offs);
  bin_scatter<<<NBB,256,0,stream>>>(receivers, bcur, eeid, er16);
  bin_finalize<<<NBINS,256,0,stream>>>(eeid, er16, bof2, bcnt, offs, buck);
  fused_edge<<<N_NODES/16, 256, 0, stream>>>(buck, offs, radial_emb, edge_sh,
                                             senders, sv16, wbuf,
                                             node_scalars, node_vectors, species,
                                             d_out, flag);
}

// Round 7
// 414.040 us; speedup vs baseline: 2.3730x; 2.3730x over previous
//
#include <hip/hip_runtime.h>
#include <hip/hip_bf16.h>

typedef unsigned short u16;
typedef unsigned int   u32;
typedef _Float16 h2 __attribute__((ext_vector_type(2)));
typedef short s8v __attribute__((ext_vector_type(8)));
typedef float f4v __attribute__((ext_vector_type(4)));
typedef u16 u16x4 __attribute__((ext_vector_type(4)));

#define N_NODES 50000
#define N_EDGES 800000
#define NCH   2
#define RPC   25000      // receivers per chunk
#define CHMAX 409600     // max edges per chunk (mean 400k, +21 sigma)

// binned bucket construction
#define RPB   250        // receivers per bin (chunk boundary 25000 = bin 100, aligned)
#define NBINS 200
#define EPB   4096       // edges per block in binning kernels
#define NBB   ((N_EDGES+EPB-1)/EPB)   // 196

// ---- ws layout (u32 units), total ~34.4M u32 = 137.5 MB ----
#define WB_W1H  0        // [64][4] u32 half2 (fp16 pairs of W1 columns)
#define WB_B1   256      // [64] f32
#define WB_W2F  320      // 5120 bf16 = 2560 u32, MFMA B-frag layout
#define WB_WINS 2880
#define WB_WINV 3136
#define WB_WOS  3392
#define WB_WOV  4416
#define WB_SCS  5184
#define WB_SCV  7232
#define WB_FLAG 8256
#define OFF_SV16 8260    // [50000][16][4] u16 (xs,x0,x1,x2)
#define IDX_BCNT 1608260 // 200 ints
#define IDX_BOF2 1608516 // 200 ints
#define IDX_BCUR 1608772 // 200 ints
#define IDX_OFFS 1658260 // 50001 ints
#define IDX_BUCK 1758262 // 800,000 int
#define IDX_EEID 2558264 // 800,000 u32 (bin-grouped edge ids)
#define OFF_ER16 3358264 // 800,000 u16 (bin-grouped receivers)
#define OFF_WP   3758264 // [CHMAX][16][8] u16 = 26,214,400 u32
#define ACC_OFF  29972664 // 25,000 x 176 f32 per-chunk accumulators

__device__ __forceinline__ float bf2f(u16 v){
  union { u32 u; float f; } x; x.u = ((u32)v) << 16; return x.f;
}
__device__ __forceinline__ u16 f2bf(float f){
  u32 u = __float_as_uint(f);
  u32 lsb = (u >> 16) & 1u;
  u32 r = u + 0x7fffu + lsb;
  return (u16)(r >> 16);
}
__device__ __forceinline__ float ldx(const void* p, long long i, int isf){
  return isf ? ((const float*)p)[i] : bf2f(((const u16*)p)[i]);
}
__device__ __forceinline__ u32 pkh2(float a, float b){
  union { u32 u; h2 v; } x; x.v.x = (_Float16)a; x.v.y = (_Float16)b; return x.u;
}
__device__ __forceinline__ float dot2(h2 a, u32 w, float c){
  union { u32 u; h2 v; } x; x.u = w;
#if __has_builtin(__builtin_amdgcn_fdot2)
  return __builtin_amdgcn_fdot2(a, x.v, c, false);
#else
  return c + (float)a.x*(float)x.v.x + (float)a.y*(float)x.v.y;
#endif
}
__device__ __forceinline__ float sigmoidf_(float x){ return 1.f/(1.f + __expf(-x)); }

__global__ void detect_dtype(const u32* __restrict__ remb_raw, int* __restrict__ flag){
  int t = threadIdx.x;           // 64 lanes, one word each
  u32 w = remb_raw[t];
  u32 lo = w & 0xffffu, hi = w >> 16;
  int okl = ((lo & 0x8000u) == 0) && (((lo >> 7) & 0xffu) <= 126u);
  int okh = ((hi & 0x8000u) == 0) && (((hi >> 7) & 0xffu) <= 126u);
  unsigned long long bad = __ballot(!(okl && okh));
  if (t == 0) *flag = (bad != 0ull) ? 1 : 0;
}

__global__ void prep_weights(const void* __restrict__ w1, const void* __restrict__ b1g,
                             const void* __restrict__ w2, const void* __restrict__ wins,
                             const void* __restrict__ winv, const void* __restrict__ wos,
                             const void* __restrict__ wov, const void* __restrict__ scs,
                             const void* __restrict__ scv, float* __restrict__ wbuf,
                             const int* __restrict__ flag){
  int t = threadIdx.x;
  int isf = *flag;
  u32* w1h  = (u32*)(wbuf + WB_W1H);
  u16* w2f  = (u16*)(wbuf + WB_W2F);
  for (int idx=t; idx<256;  idx+=256){
    int j = idx>>2, ip = idx&3;
    w1h[idx] = pkh2(ldx(w1, (2*ip)*64+j, isf), ldx(w1, (2*ip+1)*64+j, isf));
  }
  for (int idx=t; idx<64;   idx+=256){ wbuf[WB_B1+idx]  = ldx(b1g, idx, isf); }
  // MFMA B-frag layout for 16x16x32 bf16: lane holds B[k=(lane>>4)*8+j][n=lane&15]
  for (int idx=t; idx<5120; idx+=256){
    int tt = idx >> 10;           // N-tile 0..4
    int rem = idx & 1023;
    int kh = rem >> 9;            // K-half 0..1
    int rem2 = rem & 511;
    int ln = rem2 >> 3, j = rem2 & 7;
    int k = kh*32 + (ln>>4)*8 + j;
    int o = tt*16 + (ln&15);
    w2f[idx] = f2bf(ldx(w2, (long long)k*80 + o, isf));
  }
  for (int idx=t; idx<256;  idx+=256){ wbuf[WB_WINS+idx] = ldx(wins, idx, isf); }
  for (int idx=t; idx<256;  idx+=256){ wbuf[WB_WINV+idx] = ldx(winv, idx, isf); }
  for (int idx=t; idx<1024; idx+=256){ wbuf[WB_WOS+idx]  = ldx(wos, idx, isf); }
  for (int idx=t; idx<768;  idx+=256){ wbuf[WB_WOV+idx]  = ldx(wov, idx, isf); }
  for (int idx=t; idx<2048; idx+=256){ wbuf[WB_SCS+idx]  = ldx(scs, idx, isf); }
  for (int idx=t; idx<1024; idx+=256){ wbuf[WB_SCV+idx]  = ldx(scv, idx, isf); }
}

// one node per thread; fully vectorized 16B loads/stores; 64-thread blocks for CU spread
__global__ void __launch_bounds__(64) node_pre(
    const void* __restrict__ ns_g, const void* __restrict__ nv_g,
    const float* __restrict__ wbuf, u16* __restrict__ sv16,
    const int* __restrict__ flag){
  int n = blockIdx.x*64 + threadIdx.x;
  if (n >= N_NODES) return;
  int isf = *flag;
  float a[16], b[48];
  if (isf){
    const f4v* pa = (const f4v*)ns_g + (size_t)n*4;
    #pragma unroll
    for (int k=0;k<4;k++){
      f4v v = pa[k];
      a[k*4]=v[0]; a[k*4+1]=v[1]; a[k*4+2]=v[2]; a[k*4+3]=v[3];
    }
    const f4v* pb = (const f4v*)nv_g + (size_t)n*12;
    #pragma unroll
    for (int k=0;k<12;k++){
      f4v v = pb[k];
      b[k*4]=v[0]; b[k*4+1]=v[1]; b[k*4+2]=v[2]; b[k*4+3]=v[3];
    }
  } else {
    const s8v* pa = (const s8v*)ns_g + (size_t)n*2;
    #pragma unroll
    for (int k=0;k<2;k++){
      s8v v = pa[k];
      #pragma unroll
      for (int j=0;j<8;j++) a[k*8+j] = bf2f((u16)v[j]);
    }
    const s8v* pb = (const s8v*)nv_g + (size_t)n*6;
    #pragma unroll
    for (int k=0;k<6;k++){
      s8v v = pb[k];
      #pragma unroll
      for (int j=0;j<8;j++) b[k*8+j] = bf2f((u16)v[j]);
    }
  }
  const float* wins = wbuf + WB_WINS;
  const float* winv = wbuf + WB_WINV;
  float s[16];
  #pragma unroll
  for (int w=0;w<16;w++) s[w]=0.f;
  #pragma unroll
  for (int u=0;u<16;u++){
    float au = a[u];
    #pragma unroll
    for (int w=0;w<16;w++) s[w] += au * wins[u*16+w];
  }
  float v0[16], v1[16], v2[16];
  #pragma unroll
  for (int w=0;w<16;w++){ v0[w]=0.f; v1[w]=0.f; v2[w]=0.f; }
  #pragma unroll
  for (int u=0;u<16;u++){
    float bu0=b[u*3], bu1=b[u*3+1], bu2=b[u*3+2];
    #pragma unroll
    for (int w=0;w<16;w++){
      float wv = winv[u*16+w];
      v0[w] += bu0*wv; v1[w] += bu1*wv; v2[w] += bu2*wv;
    }
  }
  s8v* svp = (s8v*)(sv16 + (size_t)n*64);
  #pragma unroll
  for (int w=0;w<16;w+=2){
    s8v pk;
    pk[0]=(short)f2bf(s[w]);   pk[1]=(short)f2bf(v0[w]);
    pk[2]=(short)f2bf(v1[w]);  pk[3]=(short)f2bf(v2[w]);
    pk[4]=(short)f2bf(s[w+1]); pk[5]=(short)f2bf(v0[w+1]);
    pk[6]=(short)f2bf(v1[w+1]);pk[7]=(short)f2bf(v2[w+1]);
    svp[w>>1] = pk;
  }
}

// ---- binned bucket construction ----
__global__ void __launch_bounds__(256) bin_count(const int* __restrict__ receivers,
                                                 int* __restrict__ bcnt){
  __shared__ int lcnt[NBINS];
  int t = threadIdx.x;
  for (int i=t;i<NBINS;i+=256) lcnt[i]=0;
  __syncthreads();
  int base = blockIdx.x*EPB;
  for (int i=t;i<EPB;i+=256){
    int e = base+i;
    if (e<N_EDGES) atomicAdd(&lcnt[receivers[e]/RPB],1);
  }
  __syncthreads();
  for (int i=t;i<NBINS;i+=256) if (lcnt[i]) atomicAdd(&bcnt[i], lcnt[i]);
}

__global__ void bin_scan(const int* __restrict__ bcnt, int* __restrict__ binoff,
                         int* __restrict__ bincur, int* __restrict__ offs){
  __shared__ int lds[NBINS];
  int t=threadIdx.x;
  if (t<NBINS) lds[t]=bcnt[t];
  __syncthreads();
  for (int off=1; off<NBINS; off<<=1){
    int v = (t<NBINS && t>=off)? lds[t-off] : 0;
    __syncthreads();
    if (t<NBINS) lds[t]+=v;
    __syncthreads();
  }
  if (t<NBINS){ int ex = lds[t]-bcnt[t]; binoff[t]=ex; bincur[t]=ex; }
  if (t==0) offs[N_NODES] = N_EDGES;
}

__global__ void __launch_bounds__(256) bin_scatter(const int* __restrict__ receivers,
                 int* __restrict__ bincur, u32* __restrict__ eeid, u16* __restrict__ er){
  __shared__ int lcnt[NBINS], loff[NBINS], lcur[NBINS], gbase[NBINS];
  __shared__ u32 seid[EPB];
  __shared__ u16 sr[EPB];
  int t = threadIdx.x;
  for (int i=t;i<NBINS;i+=256) lcnt[i]=0;
  __syncthreads();
  int base = blockIdx.x*EPB;
  int r_[16];
  #pragma unroll
  for (int k=0;k<16;k++){
    int e = base + t + k*256;
    r_[k] = (e<N_EDGES)? receivers[e] : -1;
    if (r_[k]>=0) atomicAdd(&lcnt[r_[k]/RPB],1);
  }
  __syncthreads();
  if (t<NBINS) loff[t]=lcnt[t];
  __syncthreads();
  for (int off=1; off<NBINS; off<<=1){
    int v=(t<NBINS&&t>=off)?loff[t-off]:0;
    __syncthreads();
    if (t<NBINS) loff[t]+=v;
    __syncthreads();
  }
  if (t<NBINS){
    int ex=loff[t]-lcnt[t]; loff[t]=ex; lcur[t]=ex;
    gbase[t] = lcnt[t] ? atomicAdd(&bincur[t], lcnt[t]) : 0;
  }
  __syncthreads();
  #pragma unroll
  for (int k=0;k<16;k++){
    if (r_[k]>=0){
      int b=r_[k]/RPB;
      int p=atomicAdd(&lcur[b],1);
      seid[p]=(u32)(base + t + k*256);
      sr[p]=(u16)r_[k];
    }
  }
  __syncthreads();
  int rem = N_EDGES - base;
  int tot = rem < EPB ? rem : EPB;
  for (int i=t;i<tot;i+=256){
    int b = sr[i]/RPB;
    int dst = gbase[b] + (i - loff[b]);
    eeid[dst]=seid[i]; er[dst]=sr[i];
  }
}

__global__ void __launch_bounds__(256) bin_finalize(const u32* __restrict__ eeid,
        const u16* __restrict__ er, const int* __restrict__ binoff,
        const int* __restrict__ bcnt, int* __restrict__ offs, int* __restrict__ bucket){
  __shared__ int deg[RPB], pfx[RPB], lcur[RPB];
  int b=blockIdx.x, t=threadIdx.x;
  int beg=binoff[b], cnt=bcnt[b];
  for (int i=t;i<RPB;i+=256) deg[i]=0;
  __syncthreads();
  int r0=b*RPB;
  for (int i=t;i<cnt;i+=256) atomicAdd(&deg[er[beg+i]-r0],1);
  __syncthreads();
  if (t<RPB) pfx[t]=deg[t];
  __syncthreads();
  for (int off=1; off<RPB; off<<=1){
    int v=(t<RPB&&t>=off)?pfx[t-off]:0;
    __syncthreads();
    if (t<RPB) pfx[t]+=v;
    __syncthreads();
  }
  if (t<RPB){
    int ex=pfx[t]-deg[t]; pfx[t]=ex; lcur[t]=ex;
    offs[r0+t]=beg+ex;
  }
  __syncthreads();
  for (int i=t;i<cnt;i+=256){
    int rr = er[beg+i]-r0;
    int k = atomicAdd(&lcur[rr],1);
    bucket[beg+k] = (int)eeid[beg+i];
  }
}

// pass1: per chunk, compute w[80] per edge via MFMA. wave = 16 edges.
// wp16 layout: [edge][u][8] u16 (w0..w4, pad) -> one 16B store/load per (edge,u).
__global__ void __launch_bounds__(256) pass1_w(
    const int* __restrict__ bucket, const int* __restrict__ offs,
    const void* __restrict__ remb, const float* __restrict__ wbuf,
    u16* __restrict__ wp16, int rlo, const int* __restrict__ flag){
  __shared__ u16 hlds[4*16*72];        // 4 waves x 16 edges x 64 h (+8 pad)
  int tid = threadIdx.x;
  int lane = tid & 63, wid = tid >> 6;
  int isf = *flag;
  int chunkBeg = offs[rlo], chunkEnd = offs[rlo + RPC];
  int r0e = chunkBeg + (blockIdx.x*4 + wid)*16;
  if (r0e >= chunkEnd) return;         // whole-wave exit; no __syncthreads in kernel
  u16* hw = hlds + wid*(16*72);
  int e = lane & 15, q = lane >> 4;

  // ---- h for edge (r0e+e), j = q*16 .. q*16+15 ----
  int er = r0e + e;
  int eid = (er < chunkEnd) ? bucket[er] : 0;
  float re[8];
  if (isf){
    f4v ra = ((const f4v*)remb)[(size_t)eid*2];
    f4v rb = ((const f4v*)remb)[(size_t)eid*2+1];
    re[0]=ra[0]; re[1]=ra[1]; re[2]=ra[2]; re[3]=ra[3];
    re[4]=rb[0]; re[5]=rb[1]; re[6]=rb[2]; re[7]=rb[3];
  } else {
    s8v r8 = ((const s8v*)remb)[eid];
    #pragma unroll
    for (int i=0;i<8;i++) re[i] = bf2f((u16)r8[i]);
  }
  h2 reh[4];
  #pragma unroll
  for (int ip=0;ip<4;ip++){ reh[ip].x=(_Float16)re[2*ip]; reh[ip].y=(_Float16)re[2*ip+1]; }
  const u32* w1h = (const u32*)(wbuf + WB_W1H);
  const float* b1 = wbuf + WB_B1;
  #pragma unroll
  for (int jj=0;jj<16;jj++){
    int j = q*16 + jj;
    float a = b1[j];
    #pragma unroll
    for (int ip=0;ip<4;ip++) a = dot2(reh[ip], w1h[j*4+ip], a);
    a = a * sigmoidf_(a);
    hw[e*72 + j] = f2bf(a);
  }
  asm volatile("s_waitcnt lgkmcnt(0)" ::: "memory");  // wave-local LDS exchange

  // ---- B-frags (W2), 10 x 16B, coalesced, held in VGPRs ----
  const u16* w2f = (const u16*)(wbuf + WB_W2F);
  s8v bfr[5][2];
  #pragma unroll
  for (int t=0;t<5;t++)
    #pragma unroll
    for (int kh=0;kh<2;kh++)
      bfr[t][kh] = *(const s8v*)(w2f + ((t*2+kh)*64 + lane)*8);

  f4v acc[5];
  #pragma unroll
  for (int t=0;t<5;t++) acc[t] = (f4v){0.f,0.f,0.f,0.f};
  #pragma unroll
  for (int kh=0;kh<2;kh++){
    // A-frag: lane holds h[m=lane&15][k=kh*32 + q*8 + j]
    s8v af = *(const s8v*)(hw + e*72 + kh*32 + q*8);
    #pragma unroll
    for (int t=0;t<5;t++)
      acc[t] = __builtin_amdgcn_mfma_f32_16x16x32_bf16(af, bfr[t][kh], acc[t], 0,0,0);
  }
  // ---- store: C layout col=lane&15 (=u), row=q*4+reg (=edge in tile) ----
  // lane holds all 5 planes for (row, u=n): pack one 16B store per row.
  int n = lane & 15;
  #pragma unroll
  for (int r=0;r<4;r++){
    int er2 = r0e + q*4 + r;
    if (er2 < chunkEnd){
      size_t widx = (size_t)(er2 - chunkBeg);
      s8v pk;
      pk[0]=(short)f2bf(acc[0][r]); pk[1]=(short)f2bf(acc[1][r]);
      pk[2]=(short)f2bf(acc[2][r]); pk[3]=(short)f2bf(acc[3][r]);
      pk[4]=(short)f2bf(acc[4][r]); pk[5]=0; pk[6]=0; pk[7]=0;
      *(s8v*)(wp16 + (widx*16 + n)*8) = pk;
    }
  }
}

// pass2a: 8-way edge parallelism per receiver (2 waves/receiver, block = 2 receivers).
// Chain layout: wave pair {wsub=0,1}, lane = q*16+u -> chain id wsub*4+q (0..7), stride 8.
// Intra-wave shfl_xor reduce over q, then LDS combine across the wave pair.
__global__ void __launch_bounds__(256, 4) pass2_reduce(
    const int* __restrict__ bucket, const int* __restrict__ offs,
    const void* __restrict__ edge_sh, const int* __restrict__ senders,
    const u16* __restrict__ sv16, const u16* __restrict__ wp16,
    float* __restrict__ accbuf, int rlo, const int* __restrict__ flag){
  __shared__ float part[4][176];
  int tid = threadIdx.x;
  int lane = tid & 63, wid = tid >> 6;
  int u = lane & 15, q = lane >> 4;
  int pr = wid >> 1;                 // receiver slot within block (0..1)
  int wsub = wid & 1;                // wave within the pair
  int isf = *flag;
  int r = rlo + blockIdx.x*2 + pr;   // grid = RPC/2, exact cover
  int chunkBeg = offs[rlo];
  int beg = offs[r], end = offs[r+1];
  float As0=0.f,As1=0.f;
  float Av00=0.f,Av01=0.f,Av02=0.f, Av10=0.f,Av11=0.f,Av12=0.f, Av20=0.f,Av21=0.f,Av22=0.f;
  auto body = [&](int rank){
    int eid = bucket[rank];
    float Y0,Yv0,Yv1,Yv2;
    if (isf){
      f4v y = ((const f4v*)edge_sh)[eid];
      Y0=y[0]; Yv0=y[1]; Yv1=y[2]; Yv2=y[3];
    } else {
      u16x4 y = ((const u16x4*)edge_sh)[eid];
      Y0=bf2f(y[0]); Yv0=bf2f(y[1]); Yv1=bf2f(y[2]); Yv2=bf2f(y[3]);
    }
    int snd = senders[eid];
    s8v wv = *(const s8v*)(wp16 + ((size_t)(rank - chunkBeg)*16 + u)*8);
    float w0=bf2f((u16)wv[0]), w1=bf2f((u16)wv[1]), w2=bf2f((u16)wv[2]);
    float w3=bf2f((u16)wv[3]), w4=bf2f((u16)wv[4]);
    u16x4 sv = *(const u16x4*)(sv16 + ((size_t)snd*16 + u)*4);
    float xs=bf2f(sv[0]), x0=bf2f(sv[1]), x1=bf2f(sv[2]), x2=bf2f(sv[3]);
    As0 += w0*xs*Y0;
    As1 += w1*(x0*Yv0 + x1*Yv1 + x2*Yv2);
    float t1 = w2*xs;  Av00 += t1*Yv0; Av01 += t1*Yv1; Av02 += t1*Yv2;
    float t2 = w3*Y0;  Av10 += t2*x0;  Av11 += t2*x1;  Av12 += t2*x2;
    Av20 += w4*(x1*Yv2 - x2*Yv1);
    Av21 += w4*(x2*Yv0 - x0*Yv2);
    Av22 += w4*(x0*Yv1 - x1*Yv0);
  };
  int rank = beg + wsub*4 + q;
  for (; rank + 8 < end; rank += 16){ body(rank); body(rank+8); }
  if (rank < end) body(rank);
  // butterfly reduce across q (lane xor 16, 32) -> per-wave sums on all lanes
  #define RED2(x) { x += __shfl_xor(x,16); x += __shfl_xor(x,32); }
  RED2(As0) RED2(As1)
  RED2(Av00) RED2(Av01) RED2(Av02)
  RED2(Av10) RED2(Av11) RED2(Av12)
  RED2(Av20) RED2(Av21) RED2(Av22)
  #undef RED2
  // layout: [0,16)=As0  [16,32)=As1  32 + c*48 + p*16 + u = Av[p][c]
  if (q == 0){
    float* pp = part[wid];
    pp[u]=As0;      pp[16+u]=As1;
    pp[32+u]=Av00;  pp[48+u]=Av10;  pp[64+u]=Av20;
    pp[80+u]=Av01;  pp[96+u]=Av11;  pp[112+u]=Av21;
    pp[128+u]=Av02; pp[144+u]=Av12; pp[160+u]=Av22;
  }
  __syncthreads();
  for (int i = tid; i < 352; i += 256){
    int pr2 = i / 176, idx = i - pr2*176;
    int rr = blockIdx.x*2 + pr2;
    accbuf[(size_t)rr*176 + idx] = part[pr2*2][idx] + part[pr2*2+1][idx];
  }
}

// pass2b: dense per-node epilogue, 16 threads per node, LDS-staged accumulators.
__global__ void __launch_bounds__(256) pass2_epilogue(
    const float* __restrict__ accbuf, const float* __restrict__ wbuf,
    const void* __restrict__ ns_g, const void* __restrict__ nv_g,
    const int* __restrict__ species, void* __restrict__ out,
    int rlo, const int* __restrict__ flag){
  __shared__ float sb[16*176 + 16*16 + 16*48];   // bins | ns | vin
  int tid = threadIdx.x;
  int isf = *flag;
  int n0 = rlo + blockIdx.x*16;
  int rem = rlo + RPC - n0;
  int nblk = rem < 16 ? rem : 16;
  {
    int tot = nblk*176;
    const float* src = accbuf + (size_t)(n0 - rlo)*176;
    for (int i=tid; i<tot; i+=256) sb[i] = src[i];
    float* nsb = sb + 2816;
    for (int i=tid; i<nblk*16; i+=256)
      nsb[i] = ldx(ns_g, (long long)n0*16 + i, isf);
    float* vinb = sb + 2816 + 256;
    for (int i=tid; i<nblk*48; i+=256)
      vinb[i] = ldx(nv_g, (long long)n0*48 + i, isf);
  }
  __syncthreads();
  int g = tid >> 4, u = tid & 15;
  if (g >= nblk) return;
  int nn = n0 + g;
  const float* bin  = sb + g*176;
  const float* nsb  = sb + 2816 + g*16;
  const float* vinb = sb + 2816 + 256 + g*48;
  int sp = species[nn];
  const float* wos = wbuf + WB_WOS;
  const float* scs = wbuf + WB_SCS + sp*512;
  const float* wov = wbuf + WB_WOV;
  const float* scv = wbuf + WB_SCV + sp*256;
  float p0 = 0.f, p1 = 0.f;
  #pragma unroll
  for (int j=0;j<32;j++){
    float a = bin[j]*0.25f;
    p0 += a*wos[j*32+u];
    p1 += a*wos[j*32+16+u];
  }
  #pragma unroll
  for (int j=0;j<16;j++){
    float nu = nsb[j];
    p0 += nu*scs[j*32+u];
    p1 += nu*scs[j*32+16+u];
  }
  float gate = sigmoidf_(p1);
  float os = p0*sigmoidf_(p0) + nsb[u];
  float pv0, pv1, pv2;
  {
    float a0=0.f, a1=0.f, a2=0.f;
    #pragma unroll
    for (int j=0;j<48;j++){
      float wv = wov[j*16+u];
      a0 += bin[32 + 0*48 + j]*0.25f*wv;
      a1 += bin[32 + 1*48 + j]*0.25f*wv;
      a2 += bin[32 + 2*48 + j]*0.25f*wv;
    }
    #pragma unroll
    for (int j=0;j<16;j++){
      float sv = scv[j*16+u];
      a0 += vinb[j*3+0]*sv;
      a1 += vinb[j*3+1]*sv;
      a2 += vinb[j*3+2]*sv;
    }
    pv0 = a0*gate + vinb[u*3+0];
    pv1 = a1*gate + vinb[u*3+1];
    pv2 = a2*gate + vinb[u*3+2];
  }
  if (isf){
    float* orow = (float*)out + (size_t)nn*64;
    orow[u] = os;
    orow[16 + u*3 + 0] = pv0;
    orow[16 + u*3 + 1] = pv1;
    orow[16 + u*3 + 2] = pv2;
  } else {
    u16* orow = (u16*)out + (size_t)nn*64;
    orow[u] = f2bf(os);
    orow[16 + u*3 + 0] = f2bf(pv0);
    orow[16 + u*3 + 1] = f2bf(pv1);
    orow[16 + u*3 + 2] = f2bf(pv2);
  }
}

extern "C" void kernel_launch(void* const* d_in, const int* in_sizes, int n_in,
                              void* d_out, int out_size, void* d_ws, size_t ws_size,
                              hipStream_t stream){
  const void* node_scalars = d_in[0];
  const void* node_vectors = d_in[1];
  const void* edge_sh      = d_in[2];
  const void* radial_emb   = d_in[3];
  const int* senders      = (const int*)d_in[4];
  const int* receivers    = (const int*)d_in[5];
  const int* species      = (const int*)d_in[6];
  const void* W_in_s  = d_in[7];
  const void* W_in_v  = d_in[8];
  const void* mlp_w1  = d_in[9];
  const void* mlp_b1  = d_in[10];
  const void* mlp_w2  = d_in[11];
  const void* W_out_s = d_in[12];
  const void* W_out_v = d_in[13];
  const void* sc_s    = d_in[14];
  const void* sc_v    = d_in[15];

  float* wsf  = (float*)d_ws;
  int*   wsi  = (int*)d_ws;
  u32*   wsu  = (u32*)d_ws;
  float* wbuf = wsf;
  u16*   sv16 = (u16*)(wsu + OFF_SV16);
  int*   bcnt = wsi + IDX_BCNT;
  int*   bof2 = wsi + IDX_BOF2;
  int*   bcur = wsi + IDX_BCUR;
  int*   offs = wsi + IDX_OFFS;
  int*   buck = wsi + IDX_BUCK;
  u32*   eeid = wsu + IDX_EEID;
  u16*   er16 = (u16*)(wsu + OFF_ER16);
  u16*   wp16 = (u16*)(wsu + OFF_WP);
  float* accb = wsf + ACC_OFF;
  int*   flag = (int*)(wbuf + WB_FLAG);

  detect_dtype<<<1,64,0,stream>>>((const u32*)radial_emb, flag);
  hipMemsetAsync(bcnt, 0, NBINS*sizeof(int), stream);
  prep_weights<<<1,256,0,stream>>>(mlp_w1, mlp_b1, mlp_w2, W_in_s, W_in_v,
                                   W_out_s, W_out_v, sc_s, sc_v, wbuf, flag);
  node_pre<<<(N_NODES+63)/64,64,0,stream>>>(node_scalars, node_vectors, wbuf,
                                            sv16, flag);
  bin_count<<<NBB,256,0,stream>>>(receivers, bcnt);
  bin_scan<<<1,256,0,stream>>>(bcnt, bof2, bcur, offs);
  bin_scatter<<<NBB,256,0,stream>>>(receivers, bcur, eeid, er16);
  bin_finalize<<<NBINS,256,0,stream>>>(eeid, er16, bof2, bcnt, offs, buck);
  for (int c = 0; c < NCH; c++){
    int rlo = c * RPC;
    pass1_w<<<CHMAX/64, 256, 0, stream>>>(buck, offs, radial_emb, wbuf, wp16, rlo, flag);
    pass2_reduce<<<RPC/2, 256, 0, stream>>>(buck, offs, edge_sh, senders,
                                            sv16, wp16, accb, rlo, flag);
    pass2_epilogue<<<(RPC+15)/16, 256, 0, stream>>>(accb, wbuf, node_scalars,
                                                    node_vectors, species,
                                                    d_out, rlo, flag);
  }
}

// Round 8
// 376.165 us; speedup vs baseline: 2.6119x; 1.1007x over previous
//
#include <hip/hip_runtime.h>
#include <hip/hip_bf16.h>

typedef unsigned short u16;
typedef unsigned int   u32;
typedef _Float16 h2 __attribute__((ext_vector_type(2)));
typedef short s8v __attribute__((ext_vector_type(8)));
typedef float f4v __attribute__((ext_vector_type(4)));
typedef u16 u16x4 __attribute__((ext_vector_type(4)));

#define N_NODES 50000
#define N_EDGES 800000
#define NCH   2
#define RPC   25000      // receivers per chunk
#define CHMAX 409600     // max edges per chunk (mean 400k, +21 sigma)

// binned bucket construction
#define RPB   250        // receivers per bin (chunk boundary 25000 = bin 100, aligned)
#define NBINS 200
#define EPB   4096       // edges per block in binning kernels
#define NBB   ((N_EDGES+EPB-1)/EPB)   // 196

// ---- ws layout (u32 units), total ~26.4M u32 = 105.5 MB ----
#define WB_W1H  0        // [64][4] u32 half2 (fp16 pairs of W1 columns)
#define WB_B1   256      // [64] f32
#define WB_W2F  320      // 5120 bf16 = 2560 u32, MFMA B-frag layout
#define WB_WINS 2880
#define WB_WINV 3136
#define WB_WOS  3392
#define WB_WOV  4416
#define WB_SCS  5184
#define WB_SCV  7232
#define WB_FLAG 8256
#define OFF_SV16 8260    // [50000][16][4] u16 (xs,x0,x1,x2)
#define IDX_BCNT 1608260 // 200 ints
#define IDX_BOF2 1608516 // 200 ints
#define IDX_BCUR 1608772 // 200 ints
#define IDX_OFFS 1658260 // 50001 ints
#define IDX_BUCK 1758262 // 800,000 int
#define IDX_EEID 2558264 // 800,000 u32 (bin-grouped edge ids)
#define OFF_ER16 3358264 // 800,000 u16 (bin-grouped receivers)
#define OFF_WPA  3758264 // [CHMAX][16] u16x4 (w0..w3) = 13,107,200 u32
#define OFF_WPB  16865464 // [CHMAX][16] u16 (w4) = 3,276,800 u32
#define OFF_YB   20142264 // [CHMAX] f4v (Y0,Yv0,Yv1,Yv2 f32, rank order) = 1,638,400 u32
#define OFF_SND  21780664 // [CHMAX] u16 (sender, rank order) = 204,800 u32
#define ACC_OFF  21985464 // 25,000 x 176 f32 per-chunk accumulators

__device__ __forceinline__ float bf2f(u16 v){
  union { u32 u; float f; } x; x.u = ((u32)v) << 16; return x.f;
}
__device__ __forceinline__ u16 f2bf(float f){
  u32 u = __float_as_uint(f);
  u32 lsb = (u >> 16) & 1u;
  u32 r = u + 0x7fffu + lsb;
  return (u16)(r >> 16);
}
__device__ __forceinline__ float ldx(const void* p, long long i, int isf){
  return isf ? ((const float*)p)[i] : bf2f(((const u16*)p)[i]);
}
__device__ __forceinline__ u32 pkh2(float a, float b){
  union { u32 u; h2 v; } x; x.v.x = (_Float16)a; x.v.y = (_Float16)b; return x.u;
}
__device__ __forceinline__ float dot2(h2 a, u32 w, float c){
  union { u32 u; h2 v; } x; x.u = w;
#if __has_builtin(__builtin_amdgcn_fdot2)
  return __builtin_amdgcn_fdot2(a, x.v, c, false);
#else
  return c + (float)a.x*(float)x.v.x + (float)a.y*(float)x.v.y;
#endif
}
__device__ __forceinline__ float sigmoidf_(float x){ return 1.f/(1.f + __expf(-x)); }

__global__ void detect_dtype(const u32* __restrict__ remb_raw, int* __restrict__ flag){
  int t = threadIdx.x;           // 64 lanes, one word each
  u32 w = remb_raw[t];
  u32 lo = w & 0xffffu, hi = w >> 16;
  int okl = ((lo & 0x8000u) == 0) && (((lo >> 7) & 0xffu) <= 126u);
  int okh = ((hi & 0x8000u) == 0) && (((hi >> 7) & 0xffu) <= 126u);
  unsigned long long bad = __ballot(!(okl && okh));
  if (t == 0) *flag = (bad != 0ull) ? 1 : 0;
}

__global__ void prep_weights(const void* __restrict__ w1, const void* __restrict__ b1g,
                             const void* __restrict__ w2, const void* __restrict__ wins,
                             const void* __restrict__ winv, const void* __restrict__ wos,
                             const void* __restrict__ wov, const void* __restrict__ scs,
                             const void* __restrict__ scv, float* __restrict__ wbuf,
                             const int* __restrict__ flag){
  int t = threadIdx.x;
  int isf = *flag;
  u32* w1h  = (u32*)(wbuf + WB_W1H);
  u16* w2f  = (u16*)(wbuf + WB_W2F);
  for (int idx=t; idx<256;  idx+=256){
    int j = idx>>2, ip = idx&3;
    w1h[idx] = pkh2(ldx(w1, (2*ip)*64+j, isf), ldx(w1, (2*ip+1)*64+j, isf));
  }
  for (int idx=t; idx<64;   idx+=256){ wbuf[WB_B1+idx]  = ldx(b1g, idx, isf); }
  // MFMA B-frag layout for 16x16x32 bf16: lane holds B[k=(lane>>4)*8+j][n=lane&15]
  for (int idx=t; idx<5120; idx+=256){
    int tt = idx >> 10;           // N-tile 0..4
    int rem = idx & 1023;
    int kh = rem >> 9;            // K-half 0..1
    int rem2 = rem & 511;
    int ln = rem2 >> 3, j = rem2 & 7;
    int k = kh*32 + (ln>>4)*8 + j;
    int o = tt*16 + (ln&15);
    w2f[idx] = f2bf(ldx(w2, (long long)k*80 + o, isf));
  }
  for (int idx=t; idx<256;  idx+=256){ wbuf[WB_WINS+idx] = ldx(wins, idx, isf); }
  for (int idx=t; idx<256;  idx+=256){ wbuf[WB_WINV+idx] = ldx(winv, idx, isf); }
  for (int idx=t; idx<1024; idx+=256){ wbuf[WB_WOS+idx]  = ldx(wos, idx, isf); }
  for (int idx=t; idx<768;  idx+=256){ wbuf[WB_WOV+idx]  = ldx(wov, idx, isf); }
  for (int idx=t; idx<2048; idx+=256){ wbuf[WB_SCS+idx]  = ldx(scs, idx, isf); }
  for (int idx=t; idx<1024; idx+=256){ wbuf[WB_SCV+idx]  = ldx(scv, idx, isf); }
}

// one node per thread; fully vectorized 16B loads/stores; 64-thread blocks for CU spread
__global__ void __launch_bounds__(64) node_pre(
    const void* __restrict__ ns_g, const void* __restrict__ nv_g,
    const float* __restrict__ wbuf, u16* __restrict__ sv16,
    const int* __restrict__ flag){
  int n = blockIdx.x*64 + threadIdx.x;
  if (n >= N_NODES) return;
  int isf = *flag;
  float a[16], b[48];
  if (isf){
    const f4v* pa = (const f4v*)ns_g + (size_t)n*4;
    #pragma unroll
    for (int k=0;k<4;k++){
      f4v v = pa[k];
      a[k*4]=v[0]; a[k*4+1]=v[1]; a[k*4+2]=v[2]; a[k*4+3]=v[3];
    }
    const f4v* pb = (const f4v*)nv_g + (size_t)n*12;
    #pragma unroll
    for (int k=0;k<12;k++){
      f4v v = pb[k];
      b[k*4]=v[0]; b[k*4+1]=v[1]; b[k*4+2]=v[2]; b[k*4+3]=v[3];
    }
  } else {
    const s8v* pa = (const s8v*)ns_g + (size_t)n*2;
    #pragma unroll
    for (int k=0;k<2;k++){
      s8v v = pa[k];
      #pragma unroll
      for (int j=0;j<8;j++) a[k*8+j] = bf2f((u16)v[j]);
    }
    const s8v* pb = (const s8v*)nv_g + (size_t)n*6;
    #pragma unroll
    for (int k=0;k<6;k++){
      s8v v = pb[k];
      #pragma unroll
      for (int j=0;j<8;j++) b[k*8+j] = bf2f((u16)v[j]);
    }
  }
  const float* wins = wbuf + WB_WINS;
  const float* winv = wbuf + WB_WINV;
  float s[16];
  #pragma unroll
  for (int w=0;w<16;w++) s[w]=0.f;
  #pragma unroll
  for (int u=0;u<16;u++){
    float au = a[u];
    #pragma unroll
    for (int w=0;w<16;w++) s[w] += au * wins[u*16+w];
  }
  float v0[16], v1[16], v2[16];
  #pragma unroll
  for (int w=0;w<16;w++){ v0[w]=0.f; v1[w]=0.f; v2[w]=0.f; }
  #pragma unroll
  for (int u=0;u<16;u++){
    float bu0=b[u*3], bu1=b[u*3+1], bu2=b[u*3+2];
    #pragma unroll
    for (int w=0;w<16;w++){
      float wv = winv[u*16+w];
      v0[w] += bu0*wv; v1[w] += bu1*wv; v2[w] += bu2*wv;
    }
  }
  s8v* svp = (s8v*)(sv16 + (size_t)n*64);
  #pragma unroll
  for (int w=0;w<16;w+=2){
    s8v pk;
    pk[0]=(short)f2bf(s[w]);   pk[1]=(short)f2bf(v0[w]);
    pk[2]=(short)f2bf(v1[w]);  pk[3]=(short)f2bf(v2[w]);
    pk[4]=(short)f2bf(s[w+1]); pk[5]=(short)f2bf(v0[w+1]);
    pk[6]=(short)f2bf(v1[w+1]);pk[7]=(short)f2bf(v2[w+1]);
    svp[w>>1] = pk;
  }
}

// ---- binned bucket construction ----
__global__ void __launch_bounds__(256) bin_count(const int* __restrict__ receivers,
                                                 int* __restrict__ bcnt){
  __shared__ int lcnt[NBINS];
  int t = threadIdx.x;
  for (int i=t;i<NBINS;i+=256) lcnt[i]=0;
  __syncthreads();
  int base = blockIdx.x*EPB;
  for (int i=t;i<EPB;i+=256){
    int e = base+i;
    if (e<N_EDGES) atomicAdd(&lcnt[receivers[e]/RPB],1);
  }
  __syncthreads();
  for (int i=t;i<NBINS;i+=256) if (lcnt[i]) atomicAdd(&bcnt[i], lcnt[i]);
}

__global__ void bin_scan(const int* __restrict__ bcnt, int* __restrict__ binoff,
                         int* __restrict__ bincur, int* __restrict__ offs){
  __shared__ int lds[NBINS];
  int t=threadIdx.x;
  if (t<NBINS) lds[t]=bcnt[t];
  __syncthreads();
  for (int off=1; off<NBINS; off<<=1){
    int v = (t<NBINS && t>=off)? lds[t-off] : 0;
    __syncthreads();
    if (t<NBINS) lds[t]+=v;
    __syncthreads();
  }
  if (t<NBINS){ int ex = lds[t]-bcnt[t]; binoff[t]=ex; bincur[t]=ex; }
  if (t==0) offs[N_NODES] = N_EDGES;
}

__global__ void __launch_bounds__(256) bin_scatter(const int* __restrict__ receivers,
                 int* __restrict__ bincur, u32* __restrict__ eeid, u16* __restrict__ er){
  __shared__ int lcnt[NBINS], loff[NBINS], lcur[NBINS], gbase[NBINS];
  __shared__ u32 seid[EPB];
  __shared__ u16 sr[EPB];
  int t = threadIdx.x;
  for (int i=t;i<NBINS;i+=256) lcnt[i]=0;
  __syncthreads();
  int base = blockIdx.x*EPB;
  int r_[16];
  #pragma unroll
  for (int k=0;k<16;k++){
    int e = base + t + k*256;
    r_[k] = (e<N_EDGES)? receivers[e] : -1;
    if (r_[k]>=0) atomicAdd(&lcnt[r_[k]/RPB],1);
  }
  __syncthreads();
  if (t<NBINS) loff[t]=lcnt[t];
  __syncthreads();
  for (int off=1; off<NBINS; off<<=1){
    int v=(t<NBINS&&t>=off)?loff[t-off]:0;
    __syncthreads();
    if (t<NBINS) loff[t]+=v;
    __syncthreads();
  }
  if (t<NBINS){
    int ex=loff[t]-lcnt[t]; loff[t]=ex; lcur[t]=ex;
    gbase[t] = lcnt[t] ? atomicAdd(&bincur[t], lcnt[t]) : 0;
  }
  __syncthreads();
  #pragma unroll
  for (int k=0;k<16;k++){
    if (r_[k]>=0){
      int b=r_[k]/RPB;
      int p=atomicAdd(&lcur[b],1);
      seid[p]=(u32)(base + t + k*256);
      sr[p]=(u16)r_[k];
    }
  }
  __syncthreads();
  int rem = N_EDGES - base;
  int tot = rem < EPB ? rem : EPB;
  for (int i=t;i<tot;i+=256){
    int b = sr[i]/RPB;
    int dst = gbase[b] + (i - loff[b]);
    eeid[dst]=seid[i]; er[dst]=sr[i];
  }
}

__global__ void __launch_bounds__(256) bin_finalize(const u32* __restrict__ eeid,
        const u16* __restrict__ er, const int* __restrict__ binoff,
        const int* __restrict__ bcnt, int* __restrict__ offs, int* __restrict__ bucket){
  __shared__ int deg[RPB], pfx[RPB], lcur[RPB];
  int b=blockIdx.x, t=threadIdx.x;
  int beg=binoff[b], cnt=bcnt[b];
  for (int i=t;i<RPB;i+=256) deg[i]=0;
  __syncthreads();
  int r0=b*RPB;
  for (int i=t;i<cnt;i+=256) atomicAdd(&deg[er[beg+i]-r0],1);
  __syncthreads();
  if (t<RPB) pfx[t]=deg[t];
  __syncthreads();
  for (int off=1; off<RPB; off<<=1){
    int v=(t<RPB&&t>=off)?pfx[t-off]:0;
    __syncthreads();
    if (t<RPB) pfx[t]+=v;
    __syncthreads();
  }
  if (t<RPB){
    int ex=pfx[t]-deg[t]; pfx[t]=ex; lcur[t]=ex;
    offs[r0+t]=beg+ex;
  }
  __syncthreads();
  for (int i=t;i<cnt;i+=256){
    int rr = er[beg+i]-r0;
    int k = atomicAdd(&lcur[rr],1);
    bucket[beg+k] = (int)eeid[beg+i];
  }
}

// pass1: per chunk, compute w[80] per edge via MFMA; wave = 16 edges.
// Outputs (all chunk-local rank order):
//   wpA [edge][u] u16x4 = w0..w3 bf16; wpB [edge][u] u16 = w4 bf16
//   ybf [edge] f4v = edge_sh (f32, exact); snd16 [edge] u16 = sender
__global__ void __launch_bounds__(256) pass1_w(
    const int* __restrict__ bucket, const int* __restrict__ offs,
    const void* __restrict__ remb, const void* __restrict__ edge_sh,
    const int* __restrict__ senders, const float* __restrict__ wbuf,
    u16* __restrict__ wpA, u16* __restrict__ wpB,
    float* __restrict__ ybf, u16* __restrict__ snd16,
    int rlo, const int* __restrict__ flag){
  __shared__ u16 hlds[4*16*72];        // 4 waves x 16 edges x 64 h (+8 pad)
  int tid = threadIdx.x;
  int lane = tid & 63, wid = tid >> 6;
  int isf = *flag;
  int chunkBeg = offs[rlo], chunkEnd = offs[rlo + RPC];
  int r0e = chunkBeg + (blockIdx.x*4 + wid)*16;
  if (r0e >= chunkEnd) return;         // whole-wave exit; no __syncthreads in kernel
  u16* hw = hlds + wid*(16*72);
  int e = lane & 15, q = lane >> 4;

  // ---- h for edge (r0e+e), j = q*16 .. q*16+15 ----
  int er = r0e + e;
  int eid = (er < chunkEnd) ? bucket[er] : 0;
  // rank-order side tables (one writer per edge: q==0 lanes)
  if (q == 0 && er < chunkEnd){
    size_t widx = (size_t)(er - chunkBeg);
    snd16[widx] = (u16)senders[eid];
    f4v y;
    if (isf){
      y = ((const f4v*)edge_sh)[eid];
    } else {
      u16x4 yb = ((const u16x4*)edge_sh)[eid];
      y[0]=bf2f(yb[0]); y[1]=bf2f(yb[1]); y[2]=bf2f(yb[2]); y[3]=bf2f(yb[3]);
    }
    ((f4v*)ybf)[widx] = y;
  }
  float re[8];
  if (isf){
    f4v ra = ((const f4v*)remb)[(size_t)eid*2];
    f4v rb = ((const f4v*)remb)[(size_t)eid*2+1];
    re[0]=ra[0]; re[1]=ra[1]; re[2]=ra[2]; re[3]=ra[3];
    re[4]=rb[0]; re[5]=rb[1]; re[6]=rb[2]; re[7]=rb[3];
  } else {
    s8v r8 = ((const s8v*)remb)[eid];
    #pragma unroll
    for (int i=0;i<8;i++) re[i] = bf2f((u16)r8[i]);
  }
  h2 reh[4];
  #pragma unroll
  for (int ip=0;ip<4;ip++){ reh[ip].x=(_Float16)re[2*ip]; reh[ip].y=(_Float16)re[2*ip+1]; }
  const u32* w1h = (const u32*)(wbuf + WB_W1H);
  const float* b1 = wbuf + WB_B1;
  #pragma unroll
  for (int jj=0;jj<16;jj++){
    int j = q*16 + jj;
    float a = b1[j];
    #pragma unroll
    for (int ip=0;ip<4;ip++) a = dot2(reh[ip], w1h[j*4+ip], a);
    a = a * sigmoidf_(a);
    hw[e*72 + j] = f2bf(a);
  }
  asm volatile("s_waitcnt lgkmcnt(0)" ::: "memory");  // wave-local LDS exchange

  // ---- B-frags (W2), 10 x 16B, coalesced, held in VGPRs ----
  const u16* w2f = (const u16*)(wbuf + WB_W2F);
  s8v bfr[5][2];
  #pragma unroll
  for (int t=0;t<5;t++)
    #pragma unroll
    for (int kh=0;kh<2;kh++)
      bfr[t][kh] = *(const s8v*)(w2f + ((t*2+kh)*64 + lane)*8);

  f4v acc[5];
  #pragma unroll
  for (int t=0;t<5;t++) acc[t] = (f4v){0.f,0.f,0.f,0.f};
  #pragma unroll
  for (int kh=0;kh<2;kh++){
    // A-frag: lane holds h[m=lane&15][k=kh*32 + q*8 + j]
    s8v af = *(const s8v*)(hw + e*72 + kh*32 + q*8);
    #pragma unroll
    for (int t=0;t<5;t++)
      acc[t] = __builtin_amdgcn_mfma_f32_16x16x32_bf16(af, bfr[t][kh], acc[t], 0,0,0);
  }
  // ---- store: C layout col=lane&15 (=u), row=q*4+reg (=edge in tile) ----
  int n = lane & 15;
  #pragma unroll
  for (int r=0;r<4;r++){
    int er2 = r0e + q*4 + r;
    if (er2 < chunkEnd){
      size_t widx = (size_t)(er2 - chunkBeg);
      u16x4 pk4;
      pk4[0]=f2bf(acc[0][r]); pk4[1]=f2bf(acc[1][r]);
      pk4[2]=f2bf(acc[2][r]); pk4[3]=f2bf(acc[3][r]);
      ((u16x4*)wpA)[widx*16 + n] = pk4;
      wpB[widx*16 + n] = f2bf(acc[4][r]);
    }
  }
}

// pass2a: 8-way edge parallelism per receiver (2 waves/receiver, block = 2 receivers).
// All per-edge inputs are rank-ordered streams (wpA/wpB/ybf/snd16); only sv16 is a
// gather, and its chain is depth 1 (snd16 is streamed). Intra-wave shfl_xor reduce
// over q, then LDS combine across the wave pair.
__global__ void __launch_bounds__(256, 4) pass2_reduce(
    const int* __restrict__ offs,
    const u16* __restrict__ sv16, const u16* __restrict__ wpA,
    const u16* __restrict__ wpB, const float* __restrict__ ybf,
    const u16* __restrict__ snd16, float* __restrict__ accbuf,
    int rlo){
  __shared__ float part[4][176];
  int tid = threadIdx.x;
  int lane = tid & 63, wid = tid >> 6;
  int u = lane & 15, q = lane >> 4;
  int pr = wid >> 1;                 // receiver slot within block (0..1)
  int wsub = wid & 1;                // wave within the pair
  int r = rlo + blockIdx.x*2 + pr;   // grid = RPC/2, exact cover
  int chunkBeg = offs[rlo];
  int beg = offs[r], end = offs[r+1];
  float As0=0.f,As1=0.f;
  float Av00=0.f,Av01=0.f,Av02=0.f, Av10=0.f,Av11=0.f,Av12=0.f, Av20=0.f,Av21=0.f,Av22=0.f;
  auto body = [&](int rank){
    size_t li = (size_t)(rank - chunkBeg);
    f4v y = ((const f4v*)ybf)[li];
    float Y0=y[0], Yv0=y[1], Yv1=y[2], Yv2=y[3];
    int snd = snd16[li];
    u16x4 wv = ((const u16x4*)wpA)[li*16 + u];
    float w0=bf2f(wv[0]), w1=bf2f(wv[1]), w2=bf2f(wv[2]), w3=bf2f(wv[3]);
    float w4=bf2f(wpB[li*16 + u]);
    u16x4 sv = *(const u16x4*)(sv16 + ((size_t)snd*16 + u)*4);
    float xs=bf2f(sv[0]), x0=bf2f(sv[1]), x1=bf2f(sv[2]), x2=bf2f(sv[3]);
    As0 += w0*xs*Y0;
    As1 += w1*(x0*Yv0 + x1*Yv1 + x2*Yv2);
    float t1 = w2*xs;  Av00 += t1*Yv0; Av01 += t1*Yv1; Av02 += t1*Yv2;
    float t2 = w3*Y0;  Av10 += t2*x0;  Av11 += t2*x1;  Av12 += t2*x2;
    Av20 += w4*(x1*Yv2 - x2*Yv1);
    Av21 += w4*(x2*Yv0 - x0*Yv2);
    Av22 += w4*(x0*Yv1 - x1*Yv0);
  };
  int rank = beg + wsub*4 + q;
  for (; rank + 8 < end; rank += 16){ body(rank); body(rank+8); }
  if (rank < end) body(rank);
  // butterfly reduce across q (lane xor 16, 32) -> per-wave sums on all lanes
  #define RED2(x) { x += __shfl_xor(x,16); x += __shfl_xor(x,32); }
  RED2(As0) RED2(As1)
  RED2(Av00) RED2(Av01) RED2(Av02)
  RED2(Av10) RED2(Av11) RED2(Av12)
  RED2(Av20) RED2(Av21) RED2(Av22)
  #undef RED2
  // layout: [0,16)=As0  [16,32)=As1  32 + c*48 + p*16 + u = Av[p][c]
  if (q == 0){
    float* pp = part[wid];
    pp[u]=As0;      pp[16+u]=As1;
    pp[32+u]=Av00;  pp[48+u]=Av10;  pp[64+u]=Av20;
    pp[80+u]=Av01;  pp[96+u]=Av11;  pp[112+u]=Av21;
    pp[128+u]=Av02; pp[144+u]=Av12; pp[160+u]=Av22;
  }
  __syncthreads();
  for (int i = tid; i < 352; i += 256){
    int pr2 = i / 176, idx = i - pr2*176;
    int rr = blockIdx.x*2 + pr2;
    accbuf[(size_t)rr*176 + idx] = part[pr2*2][idx] + part[pr2*2+1][idx];
  }
}

// pass2b: dense per-node epilogue, 16 threads per node, LDS-staged accumulators.
__global__ void __launch_bounds__(256) pass2_epilogue(
    const float* __restrict__ accbuf, const float* __restrict__ wbuf,
    const void* __restrict__ ns_g, const void* __restrict__ nv_g,
    const int* __restrict__ species, void* __restrict__ out,
    int rlo, const int* __restrict__ flag){
  __shared__ float sb[16*176 + 16*16 + 16*48];   // bins | ns | vin
  int tid = threadIdx.x;
  int isf = *flag;
  int n0 = rlo + blockIdx.x*16;
  int rem = rlo + RPC - n0;
  int nblk = rem < 16 ? rem : 16;
  {
    int tot = nblk*176;
    const float* src = accbuf + (size_t)(n0 - rlo)*176;
    for (int i=tid; i<tot; i+=256) sb[i] = src[i];
    float* nsb = sb + 2816;
    for (int i=tid; i<nblk*16; i+=256)
      nsb[i] = ldx(ns_g, (long long)n0*16 + i, isf);
    float* vinb = sb + 2816 + 256;
    for (int i=tid; i<nblk*48; i+=256)
      vinb[i] = ldx(nv_g, (long long)n0*48 + i, isf);
  }
  __syncthreads();
  int g = tid >> 4, u = tid & 15;
  if (g >= nblk) return;
  int nn = n0 + g;
  const float* bin  = sb + g*176;
  const float* nsb  = sb + 2816 + g*16;
  const float* vinb = sb + 2816 + 256 + g*48;
  int sp = species[nn];
  const float* wos = wbuf + WB_WOS;
  const float* scs = wbuf + WB_SCS + sp*512;
  const float* wov = wbuf + WB_WOV;
  const float* scv = wbuf + WB_SCV + sp*256;
  float p0 = 0.f, p1 = 0.f;
  #pragma unroll
  for (int j=0;j<32;j++){
    float a = bin[j]*0.25f;
    p0 += a*wos[j*32+u];
    p1 += a*wos[j*32+16+u];
  }
  #pragma unroll
  for (int j=0;j<16;j++){
    float nu = nsb[j];
    p0 += nu*scs[j*32+u];
    p1 += nu*scs[j*32+16+u];
  }
  float gate = sigmoidf_(p1);
  float os = p0*sigmoidf_(p0) + nsb[u];
  float pv0, pv1, pv2;
  {
    float a0=0.f, a1=0.f, a2=0.f;
    #pragma unroll
    for (int j=0;j<48;j++){
      float wv = wov[j*16+u];
      a0 += bin[32 + 0*48 + j]*0.25f*wv;
      a1 += bin[32 + 1*48 + j]*0.25f*wv;
      a2 += bin[32 + 2*48 + j]*0.25f*wv;
    }
    #pragma unroll
    for (int j=0;j<16;j++){
      float sv = scv[j*16+u];
      a0 += vinb[j*3+0]*sv;
      a1 += vinb[j*3+1]*sv;
      a2 += vinb[j*3+2]*sv;
    }
    pv0 = a0*gate + vinb[u*3+0];
    pv1 = a1*gate + vinb[u*3+1];
    pv2 = a2*gate + vinb[u*3+2];
  }
  if (isf){
    float* orow = (float*)out + (size_t)nn*64;
    orow[u] = os;
    orow[16 + u*3 + 0] = pv0;
    orow[16 + u*3 + 1] = pv1;
    orow[16 + u*3 + 2] = pv2;
  } else {
    u16* orow = (u16*)out + (size_t)nn*64;
    orow[u] = f2bf(os);
    orow[16 + u*3 + 0] = f2bf(pv0);
    orow[16 + u*3 + 1] = f2bf(pv1);
    orow[16 + u*3 + 2] = f2bf(pv2);
  }
}

extern "C" void kernel_launch(void* const* d_in, const int* in_sizes, int n_in,
                              void* d_out, int out_size, void* d_ws, size_t ws_size,
                              hipStream_t stream){
  const void* node_scalars = d_in[0];
  const void* node_vectors = d_in[1];
  const void* edge_sh      = d_in[2];
  const void* radial_emb   = d_in[3];
  const int* senders      = (const int*)d_in[4];
  const int* receivers    = (const int*)d_in[5];
  const int* species      = (const int*)d_in[6];
  const void* W_in_s  = d_in[7];
  const void* W_in_v  = d_in[8];
  const void* mlp_w1  = d_in[9];
  const void* mlp_b1  = d_in[10];
  const void* mlp_w2  = d_in[11];
  const void* W_out_s = d_in[12];
  const void* W_out_v = d_in[13];
  const void* sc_s    = d_in[14];
  const void* sc_v    = d_in[15];

  float* wsf  = (float*)d_ws;
  int*   wsi  = (int*)d_ws;
  u32*   wsu  = (u32*)d_ws;
  float* wbuf = wsf;
  u16*   sv16 = (u16*)(wsu + OFF_SV16);
  int*   bcnt = wsi + IDX_BCNT;
  int*   bof2 = wsi + IDX_BOF2;
  int*   bcur = wsi + IDX_BCUR;
  int*   offs = wsi + IDX_OFFS;
  int*   buck = wsi + IDX_BUCK;
  u32*   eeid = wsu + IDX_EEID;
  u16*   er16 = (u16*)(wsu + OFF_ER16);
  u16*   wpA  = (u16*)(wsu + OFF_WPA);
  u16*   wpB  = (u16*)(wsu + OFF_WPB);
  float* ybf  = wsf + OFF_YB;
  u16*   snd16= (u16*)(wsu + OFF_SND);
  float* accb = wsf + ACC_OFF;
  int*   flag = (int*)(wbuf + WB_FLAG);

  detect_dtype<<<1,64,0,stream>>>((const u32*)radial_emb, flag);
  hipMemsetAsync(bcnt, 0, NBINS*sizeof(int), stream);
  prep_weights<<<1,256,0,stream>>>(mlp_w1, mlp_b1, mlp_w2, W_in_s, W_in_v,
                                   W_out_s, W_out_v, sc_s, sc_v, wbuf, flag);
  node_pre<<<(N_NODES+63)/64,64,0,stream>>>(node_scalars, node_vectors, wbuf,
                                            sv16, flag);
  bin_count<<<NBB,256,0,stream>>>(receivers, bcnt);
  bin_scan<<<1,256,0,stream>>>(bcnt, bof2, bcur, offs);
  bin_scatter<<<NBB,256,0,stream>>>(receivers, bcur, eeid, er16);
  bin_finalize<<<NBINS,256,0,stream>>>(eeid, er16, bof2, bcnt, offs, buck);
  for (int c = 0; c < NCH; c++){
    int rlo = c * RPC;
    pass1_w<<<CHMAX/64, 256, 0, stream>>>(buck, offs, radial_emb, edge_sh, senders,
                                          wbuf, wpA, wpB, ybf, snd16, rlo, flag);
    pass2_reduce<<<RPC/2, 256, 0, stream>>>(offs, sv16, wpA, wpB, ybf, snd16,
                                            accb, rlo);
    pass2_epilogue<<<(RPC+15)/16, 256, 0, stream>>>(accb, wbuf, node_scalars,
                                                    node_vectors, species,
                                                    d_out, rlo, flag);
  }
}